// Round 1
// baseline (874.771 us; speedup 1.0000x reference)
//
#include <hip/hip_runtime.h>

#define N_NODES 20000
#define N_EDGES 320000
#define HID 64
#define MDIM 8
#define ROW 512            // HID*MDIM
#define NM 160000.0f       // N_NODES*MDIM
#define NCHUNK 79          // ceil(20000/256)

// ---------------- CSR build ----------------
__global__ __launch_bounds__(256) void k_hist(const int* __restrict__ dst, int* __restrict__ deg) {
    int e = blockIdx.x * 256 + threadIdx.x;
    if (e < N_EDGES) atomicAdd(&deg[dst[e]], 1);
}

__global__ __launch_bounds__(256) void k_csum(const int* __restrict__ deg, int* __restrict__ csum) {
    __shared__ int r[256];
    int t = threadIdx.x, i = blockIdx.x * 256 + t;
    r[t] = (i < N_NODES) ? deg[i] : 0;
    __syncthreads();
    for (int s = 128; s > 0; s >>= 1) { if (t < s) r[t] += r[t + s]; __syncthreads(); }
    if (t == 0) csum[blockIdx.x] = r[0];
}

__global__ __launch_bounds__(128) void k_cscan(const int* __restrict__ csum, int* __restrict__ chunkoff) {
    __shared__ int s[128];
    int t = threadIdx.x;
    s[t] = (t < NCHUNK) ? csum[t] : 0;
    __syncthreads();
    if (t == 0) { int run = 0; for (int j = 0; j < NCHUNK; ++j) { int x = s[j]; s[j] = run; run += x; } }
    __syncthreads();
    if (t < NCHUNK) chunkoff[t] = s[t];
}

__global__ __launch_bounds__(256) void k_chunkscan(const int* __restrict__ deg, const int* __restrict__ chunkoff,
                                                   int* __restrict__ offs) {
    __shared__ int sd[256];
    int t = threadIdx.x, i = blockIdx.x * 256 + t;
    int v = (i < N_NODES) ? deg[i] : 0;
    sd[t] = v;
    __syncthreads();
    for (int off = 1; off < 256; off <<= 1) {
        int x = (t >= off) ? sd[t - off] : 0;
        __syncthreads();
        sd[t] += x;
        __syncthreads();
    }
    if (i < N_NODES) offs[i] = sd[t] - v + chunkoff[blockIdx.x];
}

__global__ __launch_bounds__(256) void k_fill(const int* __restrict__ src, const int* __restrict__ dst,
                                              const int* __restrict__ offs, int* __restrict__ cursor,
                                              int* __restrict__ esrc) {
    int e = blockIdx.x * 256 + threadIdx.x;
    if (e < N_EDGES) {
        int d = dst[e];
        int p = atomicAdd(&cursor[d], 1);
        esrc[offs[d] + p] = src[e];
    }
}

// ---------------- layer 0 aggregation (C=1): zin0[n][m] = x[n][m] + sum_nbr x[s][m]
__global__ __launch_bounds__(64) void k_agg0(const float* __restrict__ x, const int* __restrict__ offs,
                                             const int* __restrict__ deg, const int* __restrict__ esrc,
                                             float* __restrict__ zin0) {
    int n = blockIdx.x, t = threadIdx.x;
    int off = offs[n], dg = deg[n];
    __shared__ int nbr[256];
    float acc = (t < 8) ? x[n * 8 + t] : 0.f;
    for (int base = 0; base < dg; base += 256) {
        int cnt = min(256, dg - base);
        for (int j = t; j < cnt; j += 64) nbr[j] = esrc[off + base + j];
        __syncthreads();
        if (t < 8) { for (int j = 0; j < cnt; ++j) acc += x[nbr[j] * 8 + t]; }
        __syncthreads();
    }
    if (t < 8) zin0[n * 8 + t] = acc;
}

// ---------------- generic aggregation (layers 1..4), previous-layer BN folded in:
// zin = a[c]*(z[n] + sum_src z[src]) + b[c]*(deg+1)
__global__ __launch_bounds__(64) void k_agg(const float* __restrict__ z, const float* __restrict__ ab,
                                            const int* __restrict__ offs, const int* __restrict__ deg,
                                            const int* __restrict__ esrc, float* __restrict__ zin) {
    int n = blockIdx.x, t = threadIdx.x;
    int off = offs[n], dg = deg[n];
    __shared__ int nbr[256];
    const float4* self = (const float4*)(z + (size_t)n * ROW);
    float4 a0 = self[t], a1 = self[t + 64];
    for (int base = 0; base < dg; base += 256) {
        int cnt = min(256, dg - base);
        for (int j = t; j < cnt; j += 64) nbr[j] = esrc[off + base + j];
        __syncthreads();
        for (int j = 0; j < cnt; ++j) {
            const float4* r = (const float4*)(z + (size_t)nbr[j] * ROW);
            float4 r0 = r[t], r1 = r[t + 64];
            a0.x += r0.x; a0.y += r0.y; a0.z += r0.z; a0.w += r0.w;
            a1.x += r1.x; a1.y += r1.y; a1.z += r1.z; a1.w += r1.w;
        }
        __syncthreads();
    }
    float dp1 = (float)(dg + 1);
    int c0 = t >> 1, c1 = 32 + (t >> 1);
    float A0 = ab[c0], B0 = ab[64 + c0];
    float A1 = ab[c1], B1 = ab[64 + c1];
    float4 o0, o1;
    o0.x = A0 * a0.x + B0 * dp1; o0.y = A0 * a0.y + B0 * dp1;
    o0.z = A0 * a0.z + B0 * dp1; o0.w = A0 * a0.w + B0 * dp1;
    o1.x = A1 * a1.x + B1 * dp1; o1.y = A1 * a1.y + B1 * dp1;
    o1.z = A1 * a1.z + B1 * dp1; o1.w = A1 * a1.w + B1 * dp1;
    float4* zo = (float4*)(zin + (size_t)n * ROW);
    zo[t] = o0; zo[t + 64] = o1;
}

// ---------------- MLP (two 64x64 linears + relu) + BN-stat accumulation, 4 nodes/block (1/wave)
__global__ __launch_bounds__(256) void k_mlp(const float* __restrict__ zin, const float* __restrict__ W1,
                                             const float* __restrict__ B1, const float* __restrict__ W2,
                                             const float* __restrict__ B2, float* __restrict__ zout,
                                             float* __restrict__ shadow) {
    __shared__ float w1t[65 * 64];   // padded stride 65: bank-conflict-free stage+read
    __shared__ float w2t[65 * 64];
    __shared__ __align__(16) float zin_s[4 * ROW];
    __shared__ __align__(16) float z2_s[4 * ROW];
    int tid = threadIdx.x;
    for (int g = tid; g < 4096; g += 256) {
        int o = g >> 6, c = g & 63;
        w1t[c * 65 + o] = W1[g];
        w2t[c * 65 + o] = W2[g];
    }
    int n0 = blockIdx.x * 4;
    const float4* zi = (const float4*)(zin + (size_t)n0 * ROW);
    float4* zs = (float4*)zin_s;
    for (int g = tid; g < 512; g += 256) zs[g] = zi[g];
    __syncthreads();
    int w = tid >> 6, o = tid & 63;
    const float* zrow = &zin_s[w * ROW];
    float acc[8];
    float bo = B1[o];
    #pragma unroll
    for (int m = 0; m < 8; ++m) acc[m] = bo;
    #pragma unroll 8
    for (int c = 0; c < 64; ++c) {
        float wv = w1t[c * 65 + o];
        float4 za = *(const float4*)&zrow[c * 8];
        float4 zb = *(const float4*)&zrow[c * 8 + 4];
        acc[0] += wv * za.x; acc[1] += wv * za.y; acc[2] += wv * za.z; acc[3] += wv * za.w;
        acc[4] += wv * zb.x; acc[5] += wv * zb.y; acc[6] += wv * zb.z; acc[7] += wv * zb.w;
    }
    float4 t0, t1;
    t0.x = fmaxf(acc[0], 0.f); t0.y = fmaxf(acc[1], 0.f); t0.z = fmaxf(acc[2], 0.f); t0.w = fmaxf(acc[3], 0.f);
    t1.x = fmaxf(acc[4], 0.f); t1.y = fmaxf(acc[5], 0.f); t1.z = fmaxf(acc[6], 0.f); t1.w = fmaxf(acc[7], 0.f);
    float4* z2p = (float4*)&z2_s[w * ROW + o * 8];
    z2p[0] = t0; z2p[1] = t1;
    __syncthreads();
    const float* z2row = &z2_s[w * ROW];
    float bo2 = B2[o];
    #pragma unroll
    for (int m = 0; m < 8; ++m) acc[m] = bo2;
    #pragma unroll 8
    for (int c = 0; c < 64; ++c) {
        float wv = w2t[c * 65 + o];
        float4 za = *(const float4*)&z2row[c * 8];
        float4 zb = *(const float4*)&z2row[c * 8 + 4];
        acc[0] += wv * za.x; acc[1] += wv * za.y; acc[2] += wv * za.z; acc[3] += wv * za.w;
        acc[4] += wv * zb.x; acc[5] += wv * zb.y; acc[6] += wv * zb.z; acc[7] += wv * zb.w;
    }
    float s = 0.f, ss = 0.f;
    float4 r0, r1;
    float v0 = fmaxf(acc[0], 0.f), v1 = fmaxf(acc[1], 0.f), v2 = fmaxf(acc[2], 0.f), v3 = fmaxf(acc[3], 0.f);
    float v4 = fmaxf(acc[4], 0.f), v5 = fmaxf(acc[5], 0.f), v6 = fmaxf(acc[6], 0.f), v7 = fmaxf(acc[7], 0.f);
    r0.x = v0; r0.y = v1; r0.z = v2; r0.w = v3;
    r1.x = v4; r1.y = v5; r1.z = v6; r1.w = v7;
    s = v0 + v1 + v2 + v3 + v4 + v5 + v6 + v7;
    ss = v0*v0 + v1*v1 + v2*v2 + v3*v3 + v4*v4 + v5*v5 + v6*v6 + v7*v7;
    int sid = (blockIdx.x & 63) * 128;
    atomicAdd(&shadow[sid + o], s);
    atomicAdd(&shadow[sid + 64 + o], ss);
    float4* zo = (float4*)(zout + (size_t)(n0 + w) * ROW + o * 8);
    zo[0] = r0; zo[1] = r1;
}

// ---------------- layer-0 MLP: first linear is over C=1
__global__ __launch_bounds__(256) void k_mlp0(const float* __restrict__ zin0, const float* __restrict__ W10,
                                              const float* __restrict__ B1, const float* __restrict__ W2,
                                              const float* __restrict__ B2, float* __restrict__ zout,
                                              float* __restrict__ shadow) {
    __shared__ float w2t[65 * 64];
    __shared__ float zin_s[32];
    __shared__ __align__(16) float z2_s[4 * ROW];
    int tid = threadIdx.x;
    for (int g = tid; g < 4096; g += 256) {
        int o = g >> 6, c = g & 63;
        w2t[c * 65 + o] = W2[g];
    }
    if (tid < 32) zin_s[tid] = zin0[blockIdx.x * 32 + tid];
    __syncthreads();
    int w = tid >> 6, o = tid & 63;
    float w10 = W10[o], bo = B1[o];
    float4 t0, t1;
    t0.x = fmaxf(w10 * zin_s[w * 8 + 0] + bo, 0.f);
    t0.y = fmaxf(w10 * zin_s[w * 8 + 1] + bo, 0.f);
    t0.z = fmaxf(w10 * zin_s[w * 8 + 2] + bo, 0.f);
    t0.w = fmaxf(w10 * zin_s[w * 8 + 3] + bo, 0.f);
    t1.x = fmaxf(w10 * zin_s[w * 8 + 4] + bo, 0.f);
    t1.y = fmaxf(w10 * zin_s[w * 8 + 5] + bo, 0.f);
    t1.z = fmaxf(w10 * zin_s[w * 8 + 6] + bo, 0.f);
    t1.w = fmaxf(w10 * zin_s[w * 8 + 7] + bo, 0.f);
    float4* z2p = (float4*)&z2_s[w * ROW + o * 8];
    z2p[0] = t0; z2p[1] = t1;
    __syncthreads();
    const float* z2row = &z2_s[w * ROW];
    float acc[8];
    float bo2 = B2[o];
    #pragma unroll
    for (int m = 0; m < 8; ++m) acc[m] = bo2;
    #pragma unroll 8
    for (int c = 0; c < 64; ++c) {
        float wv = w2t[c * 65 + o];
        float4 za = *(const float4*)&z2row[c * 8];
        float4 zb = *(const float4*)&z2row[c * 8 + 4];
        acc[0] += wv * za.x; acc[1] += wv * za.y; acc[2] += wv * za.z; acc[3] += wv * za.w;
        acc[4] += wv * zb.x; acc[5] += wv * zb.y; acc[6] += wv * zb.z; acc[7] += wv * zb.w;
    }
    float v0 = fmaxf(acc[0], 0.f), v1 = fmaxf(acc[1], 0.f), v2 = fmaxf(acc[2], 0.f), v3 = fmaxf(acc[3], 0.f);
    float v4 = fmaxf(acc[4], 0.f), v5 = fmaxf(acc[5], 0.f), v6 = fmaxf(acc[6], 0.f), v7 = fmaxf(acc[7], 0.f);
    float s  = v0 + v1 + v2 + v3 + v4 + v5 + v6 + v7;
    float ss = v0*v0 + v1*v1 + v2*v2 + v3*v3 + v4*v4 + v5*v5 + v6*v6 + v7*v7;
    int sid = (blockIdx.x & 63) * 128;
    atomicAdd(&shadow[sid + o], s);
    atomicAdd(&shadow[sid + 64 + o], ss);
    float4 r0, r1;
    r0.x = v0; r0.y = v1; r0.z = v2; r0.w = v3;
    r1.x = v4; r1.y = v5; r1.z = v6; r1.w = v7;
    float4* zo = (float4*)(zout + (size_t)(blockIdx.x * 4 + w) * ROW + o * 8);
    zo[0] = r0; zo[1] = r1;
}

// ---------------- BN finalize: reduce 64 shadow copies -> per-channel a,b
__global__ __launch_bounds__(64) void k_bnfin(const float* __restrict__ shadow, const float* __restrict__ gamma,
                                              const float* __restrict__ beta, float* __restrict__ ab) {
    int c = threadIdx.x;
    float s = 0.f, ss = 0.f;
    for (int j = 0; j < 64; ++j) { s += shadow[j * 128 + c]; ss += shadow[j * 128 + 64 + c]; }
    float mean = s * (1.f / NM);
    float var = ss * (1.f / NM) - mean * mean;
    float a = gamma[c] * rsqrtf(var + 1e-5f);
    ab[c] = a;
    ab[64 + c] = beta[c] - mean * a;
}

// ---------------- pooling over nodes (raw z4; BN applied in k_out)
__global__ __launch_bounds__(256) void k_pool(const float* __restrict__ z, float* __restrict__ pool) {
    int idx0 = blockIdx.x * 256 + threadIdx.x;
    float s = 0.f;
    for (int idx = idx0; idx < N_NODES * ROW; idx += 65536) s += z[idx];
    atomicAdd(&pool[idx0 & 511], s);
}

__global__ __launch_bounds__(64) void k_out(const float* __restrict__ pool, const float* __restrict__ ab4,
                                            const float* __restrict__ wout, const float* __restrict__ bout,
                                            float* __restrict__ out) {
    int c = threadIdx.x;
    float a = ab4[c], b = ab4[64 + c], wv = wout[c];
    for (int m = 0; m < 8; ++m) {
        float v = wv * (a * pool[c * 8 + m] * (1.f / N_NODES) + b);
        for (int off = 32; off > 0; off >>= 1) v += __shfl_down(v, off);
        if (c == 0) out[m] = 1.f / (1.f + expf(-(v + bout[0])));
    }
}

extern "C" void kernel_launch(void* const* d_in, const int* in_sizes, int n_in,
                              void* d_out, int out_size, void* d_ws, size_t ws_size,
                              hipStream_t stream) {
    const float* x     = (const float*)d_in[0];
    const int*   ei    = (const int*)d_in[1];
    const int*   srcp  = ei;
    const int*   dstp  = ei + N_EDGES;
    const float* w1_0  = (const float*)d_in[3];
    const float* w1    = (const float*)d_in[4];   // [4][64][64]
    const float* b1    = (const float*)d_in[5];   // [5][64]
    const float* w2    = (const float*)d_in[6];   // [5][64][64]
    const float* b2    = (const float*)d_in[7];
    const float* gamma = (const float*)d_in[8];
    const float* beta  = (const float*)d_in[9];
    const float* wout  = (const float*)d_in[10];
    const float* bout  = (const float*)d_in[11];
    float* out = (float*)d_out;

    char* ws = (char*)d_ws;
    size_t off = 0;
    auto alloc = [&](size_t bytes) -> void* {
        void* p = ws + off;
        off = (off + bytes + 255) & ~(size_t)255;
        return p;
    };
    float* zA   = (float*)alloc((size_t)N_NODES * ROW * 4);   // 40.96 MB
    float* zB   = (float*)alloc((size_t)N_NODES * ROW * 4);   // 40.96 MB
    float* zin0 = (float*)alloc((size_t)N_NODES * 8 * 4);
    int* deg      = (int*)alloc(N_NODES * 4);
    int* offs     = (int*)alloc(N_NODES * 4);
    int* cursor   = (int*)alloc(N_NODES * 4);
    int* esrc     = (int*)alloc(N_EDGES * 4);
    int* csum     = (int*)alloc(NCHUNK * 4);
    int* chunkoff = (int*)alloc(NCHUNK * 4);
    float* shadow = (float*)alloc(64 * 128 * 4);
    float* ab     = (float*)alloc(5 * 128 * 4);
    float* pool   = (float*)alloc(512 * 4);

    // CSR build
    hipMemsetAsync(deg, 0, N_NODES * 4, stream);
    hipMemsetAsync(cursor, 0, N_NODES * 4, stream);
    k_hist<<<(N_EDGES + 255) / 256, 256, 0, stream>>>(dstp, deg);
    k_csum<<<NCHUNK, 256, 0, stream>>>(deg, csum);
    k_cscan<<<1, 128, 0, stream>>>(csum, chunkoff);
    k_chunkscan<<<NCHUNK, 256, 0, stream>>>(deg, chunkoff, offs);
    k_fill<<<(N_EDGES + 255) / 256, 256, 0, stream>>>(srcp, dstp, offs, cursor, esrc);

    // layer 0
    k_agg0<<<N_NODES, 64, 0, stream>>>(x, offs, deg, esrc, zin0);
    hipMemsetAsync(shadow, 0, 64 * 128 * 4, stream);
    k_mlp0<<<N_NODES / 4, 256, 0, stream>>>(zin0, w1_0, b1, w2, b2, zA, shadow);
    k_bnfin<<<1, 64, 0, stream>>>(shadow, gamma, beta, ab);

    // layers 1..4: agg reads zA (prev raw z + folded BN), mlp writes back into zA
    for (int i = 1; i <= 4; ++i) {
        k_agg<<<N_NODES, 64, 0, stream>>>(zA, ab + (i - 1) * 128, offs, deg, esrc, zB);
        hipMemsetAsync(shadow, 0, 64 * 128 * 4, stream);
        k_mlp<<<N_NODES / 4, 256, 0, stream>>>(zB, w1 + (size_t)(i - 1) * 4096, b1 + i * 64,
                                               w2 + (size_t)i * 4096, b2 + i * 64, zA, shadow);
        k_bnfin<<<1, 64, 0, stream>>>(shadow, gamma + i * 64, beta + i * 64, ab + i * 128);
    }

    // head
    hipMemsetAsync(pool, 0, 512 * 4, stream);
    k_pool<<<256, 256, 0, stream>>>(zA, pool);
    k_out<<<1, 64, 0, stream>>>(pool, ab + 4 * 128, wout, bout, out);
}

// Round 2
// 667.528 us; speedup vs baseline: 1.3105x; 1.3105x over previous
//
#include <hip/hip_runtime.h>

#define N_NODES 20000
#define N_EDGES 320000
#define HID 64
#define MDIM 8
#define ROW 512            // HID*MDIM elements per node row
#define NM 160000.0f       // N_NODES*MDIM
#define NCHUNK 79          // ceil(20000/256)

typedef unsigned int uint;
typedef unsigned short ushort;

// bf16 helpers: storage is bf16 (ushort), all arithmetic fp32
__device__ __forceinline__ float bflo(uint u) { return __uint_as_float(u << 16); }
__device__ __forceinline__ float bfhi(uint u) { return __uint_as_float(u & 0xffff0000u); }
__device__ __forceinline__ uint f2bf(float f) {   // round-to-nearest-even
    uint u = __float_as_uint(f);
    return (u + 0x7fffu + ((u >> 16) & 1u)) >> 16;
}
__device__ __forceinline__ uint pack2(float lo, float hi) { return f2bf(lo) | (f2bf(hi) << 16); }

// ---------------- CSR build ----------------
__global__ __launch_bounds__(256) void k_hist(const int* __restrict__ dst, int* __restrict__ deg) {
    int e = blockIdx.x * 256 + threadIdx.x;
    if (e < N_EDGES) atomicAdd(&deg[dst[e]], 1);
}

__global__ __launch_bounds__(256) void k_csum(const int* __restrict__ deg, int* __restrict__ csum) {
    __shared__ int r[256];
    int t = threadIdx.x, i = blockIdx.x * 256 + t;
    r[t] = (i < N_NODES) ? deg[i] : 0;
    __syncthreads();
    for (int s = 128; s > 0; s >>= 1) { if (t < s) r[t] += r[t + s]; __syncthreads(); }
    if (t == 0) csum[blockIdx.x] = r[0];
}

__global__ __launch_bounds__(128) void k_cscan(const int* __restrict__ csum, int* __restrict__ chunkoff) {
    __shared__ int s[128];
    int t = threadIdx.x;
    s[t] = (t < NCHUNK) ? csum[t] : 0;
    __syncthreads();
    if (t == 0) { int run = 0; for (int j = 0; j < NCHUNK; ++j) { int x = s[j]; s[j] = run; run += x; } }
    __syncthreads();
    if (t < NCHUNK) chunkoff[t] = s[t];
}

__global__ __launch_bounds__(256) void k_chunkscan(const int* __restrict__ deg, const int* __restrict__ chunkoff,
                                                   int* __restrict__ offs) {
    __shared__ int sd[256];
    int t = threadIdx.x, i = blockIdx.x * 256 + t;
    int v = (i < N_NODES) ? deg[i] : 0;
    sd[t] = v;
    __syncthreads();
    for (int off = 1; off < 256; off <<= 1) {
        int x = (t >= off) ? sd[t - off] : 0;
        __syncthreads();
        sd[t] += x;
        __syncthreads();
    }
    if (i < N_NODES) offs[i] = sd[t] - v + chunkoff[blockIdx.x];
}

__global__ __launch_bounds__(256) void k_fill(const int* __restrict__ src, const int* __restrict__ dst,
                                              const int* __restrict__ offs, int* __restrict__ cursor,
                                              int* __restrict__ esrc) {
    int e = blockIdx.x * 256 + threadIdx.x;
    if (e < N_EDGES) {
        int d = dst[e];
        int p = atomicAdd(&cursor[d], 1);
        esrc[offs[d] + p] = src[e];
    }
}

// ---------------- layer 0 aggregation (C=1): zin0[n][m] = x[n][m] + sum_nbr x[s][m]
__global__ __launch_bounds__(64) void k_agg0(const float* __restrict__ x, const int* __restrict__ offs,
                                             const int* __restrict__ deg, const int* __restrict__ esrc,
                                             float* __restrict__ zin0) {
    int n = blockIdx.x, t = threadIdx.x;
    int off = offs[n], dg = deg[n];
    __shared__ int nbr[256];
    float acc = (t < 8) ? x[n * 8 + t] : 0.f;
    for (int base = 0; base < dg; base += 256) {
        int cnt = min(256, dg - base);
        for (int j = t; j < cnt; j += 64) nbr[j] = esrc[off + base + j];
        __syncthreads();
        if (t < 8) { for (int j = 0; j < cnt; ++j) acc += x[nbr[j] * 8 + t]; }
        __syncthreads();
    }
    if (t < 8) zin0[n * 8 + t] = acc;
}

// ---------------- layer-0 MLP (first linear over C=1), writes bf16 z-rows
__global__ __launch_bounds__(256) void k_mlp0(const float* __restrict__ zin0, const float* __restrict__ W10,
                                              const float* __restrict__ B1, const float* __restrict__ W2,
                                              const float* __restrict__ B2, ushort* __restrict__ zout,
                                              float* __restrict__ shadow) {
    __shared__ float w2t[65 * 64];
    __shared__ float zin_s[32];
    __shared__ __align__(16) float z2_s[4 * ROW];
    int tid = threadIdx.x;
    for (int g = tid; g < 4096; g += 256) {
        int o = g >> 6, c = g & 63;
        w2t[c * 65 + o] = W2[g];
    }
    if (tid < 32) zin_s[tid] = zin0[blockIdx.x * 32 + tid];
    __syncthreads();
    int w = tid >> 6, o = tid & 63;
    float w10 = W10[o], bo = B1[o];
    float4 t0, t1;
    t0.x = fmaxf(w10 * zin_s[w * 8 + 0] + bo, 0.f);
    t0.y = fmaxf(w10 * zin_s[w * 8 + 1] + bo, 0.f);
    t0.z = fmaxf(w10 * zin_s[w * 8 + 2] + bo, 0.f);
    t0.w = fmaxf(w10 * zin_s[w * 8 + 3] + bo, 0.f);
    t1.x = fmaxf(w10 * zin_s[w * 8 + 4] + bo, 0.f);
    t1.y = fmaxf(w10 * zin_s[w * 8 + 5] + bo, 0.f);
    t1.z = fmaxf(w10 * zin_s[w * 8 + 6] + bo, 0.f);
    t1.w = fmaxf(w10 * zin_s[w * 8 + 7] + bo, 0.f);
    float4* z2p = (float4*)&z2_s[w * ROW + o * 8];
    z2p[0] = t0; z2p[1] = t1;
    __syncthreads();
    const float* z2row = &z2_s[w * ROW];
    float acc[8];
    float bo2 = B2[o];
    #pragma unroll
    for (int m = 0; m < 8; ++m) acc[m] = bo2;
    #pragma unroll 8
    for (int c = 0; c < 64; ++c) {
        float wv = w2t[c * 65 + o];
        float4 za = *(const float4*)&z2row[c * 8];
        float4 zb = *(const float4*)&z2row[c * 8 + 4];
        acc[0] += wv * za.x; acc[1] += wv * za.y; acc[2] += wv * za.z; acc[3] += wv * za.w;
        acc[4] += wv * zb.x; acc[5] += wv * zb.y; acc[6] += wv * zb.z; acc[7] += wv * zb.w;
    }
    float v0 = fmaxf(acc[0], 0.f), v1 = fmaxf(acc[1], 0.f), v2 = fmaxf(acc[2], 0.f), v3 = fmaxf(acc[3], 0.f);
    float v4 = fmaxf(acc[4], 0.f), v5 = fmaxf(acc[5], 0.f), v6 = fmaxf(acc[6], 0.f), v7 = fmaxf(acc[7], 0.f);
    float s  = v0 + v1 + v2 + v3 + v4 + v5 + v6 + v7;
    float ss = v0*v0 + v1*v1 + v2*v2 + v3*v3 + v4*v4 + v5*v5 + v6*v6 + v7*v7;
    int sid = (blockIdx.x & 63) * 128;
    atomicAdd(&shadow[sid + o], s);
    atomicAdd(&shadow[sid + 64 + o], ss);
    uint4 pk;
    pk.x = pack2(v0, v1); pk.y = pack2(v2, v3); pk.z = pack2(v4, v5); pk.w = pack2(v6, v7);
    ((uint4*)(zout + (size_t)(blockIdx.x * 4 + w) * ROW))[o] = pk;
}

// ---------------- fused layer (1..4): gather(bf16) + prev-BN fold + MLP + BN stats, 4 nodes/block
__global__ __launch_bounds__(256) void k_layer(const ushort* __restrict__ zprev, const float* __restrict__ ab,
                                               const int* __restrict__ offs, const int* __restrict__ deg,
                                               const int* __restrict__ esrc,
                                               const float* __restrict__ W1, const float* __restrict__ B1,
                                               const float* __restrict__ W2, const float* __restrict__ B2,
                                               ushort* __restrict__ zout, float* __restrict__ shadow) {
    __shared__ float w1t[65 * 64];   // padded transpose: broadcast-read conflict-free
    __shared__ float w2t[65 * 64];
    __shared__ __align__(16) float zin_s[4 * ROW];
    __shared__ __align__(16) float z2_s[4 * ROW];
    int tid = threadIdx.x;
    for (int g = tid; g < 4096; g += 256) {
        int o = g >> 6, c = g & 63;
        w1t[c * 65 + o] = W1[g];
        w2t[c * 65 + o] = W2[g];
    }
    int w = tid >> 6, t = tid & 63;
    int n = blockIdx.x * 4 + w;
    int off = offs[n], dg = deg[n];
    // ---- aggregation: lane t owns channel t (8 m-values = one uint4 of bf16)
    uint4 sv = ((const uint4*)(zprev + (size_t)n * ROW))[t];
    float a0 = bflo(sv.x), a1 = bfhi(sv.x), a2 = bflo(sv.y), a3 = bfhi(sv.y);
    float a4 = bflo(sv.z), a5 = bfhi(sv.z), a6 = bflo(sv.w), a7 = bfhi(sv.w);
    for (int base = 0; base < dg; base += 64) {
        int cnt = min(64, dg - base);
        int idx = (base + t < dg) ? esrc[off + base + t] : 0;
        for (int j = 0; j < cnt; ++j) {
            int nb = __shfl(idx, j);
            uint4 rv = ((const uint4*)(zprev + (size_t)nb * ROW))[t];
            a0 += bflo(rv.x); a1 += bfhi(rv.x); a2 += bflo(rv.y); a3 += bfhi(rv.y);
            a4 += bflo(rv.z); a5 += bfhi(rv.z); a6 += bflo(rv.w); a7 += bfhi(rv.w);
        }
    }
    // ---- fold previous layer's BN: zin = A*(sum) + B*(deg+1)
    float A = ab[t], B = ab[64 + t] * (float)(dg + 1);
    float4 q0 = make_float4(A * a0 + B, A * a1 + B, A * a2 + B, A * a3 + B);
    float4 q1 = make_float4(A * a4 + B, A * a5 + B, A * a6 + B, A * a7 + B);
    float4* zp = (float4*)&zin_s[w * ROW + t * 8];
    zp[0] = q0; zp[1] = q1;
    __syncthreads();
    // ---- linear1 + relu (lane = output channel o)
    int o = t;
    const float* zrow = &zin_s[w * ROW];
    float acc[8];
    float bo = B1[o];
    #pragma unroll
    for (int m = 0; m < 8; ++m) acc[m] = bo;
    #pragma unroll 8
    for (int c = 0; c < 64; ++c) {
        float wv = w1t[c * 65 + o];
        float4 za = *(const float4*)&zrow[c * 8];
        float4 zb = *(const float4*)&zrow[c * 8 + 4];
        acc[0] += wv * za.x; acc[1] += wv * za.y; acc[2] += wv * za.z; acc[3] += wv * za.w;
        acc[4] += wv * zb.x; acc[5] += wv * zb.y; acc[6] += wv * zb.z; acc[7] += wv * zb.w;
    }
    float4 t0, t1;
    t0.x = fmaxf(acc[0], 0.f); t0.y = fmaxf(acc[1], 0.f); t0.z = fmaxf(acc[2], 0.f); t0.w = fmaxf(acc[3], 0.f);
    t1.x = fmaxf(acc[4], 0.f); t1.y = fmaxf(acc[5], 0.f); t1.z = fmaxf(acc[6], 0.f); t1.w = fmaxf(acc[7], 0.f);
    float4* z2p = (float4*)&z2_s[w * ROW + o * 8];
    z2p[0] = t0; z2p[1] = t1;
    __syncthreads();
    // ---- linear2 + relu + BN stats + bf16 store
    const float* z2row = &z2_s[w * ROW];
    float bo2 = B2[o];
    #pragma unroll
    for (int m = 0; m < 8; ++m) acc[m] = bo2;
    #pragma unroll 8
    for (int c = 0; c < 64; ++c) {
        float wv = w2t[c * 65 + o];
        float4 za = *(const float4*)&z2row[c * 8];
        float4 zb = *(const float4*)&z2row[c * 8 + 4];
        acc[0] += wv * za.x; acc[1] += wv * za.y; acc[2] += wv * za.z; acc[3] += wv * za.w;
        acc[4] += wv * zb.x; acc[5] += wv * zb.y; acc[6] += wv * zb.z; acc[7] += wv * zb.w;
    }
    float v0 = fmaxf(acc[0], 0.f), v1 = fmaxf(acc[1], 0.f), v2 = fmaxf(acc[2], 0.f), v3 = fmaxf(acc[3], 0.f);
    float v4 = fmaxf(acc[4], 0.f), v5 = fmaxf(acc[5], 0.f), v6 = fmaxf(acc[6], 0.f), v7 = fmaxf(acc[7], 0.f);
    float s  = v0 + v1 + v2 + v3 + v4 + v5 + v6 + v7;
    float ss = v0*v0 + v1*v1 + v2*v2 + v3*v3 + v4*v4 + v5*v5 + v6*v6 + v7*v7;
    int sid = (blockIdx.x & 63) * 128;
    atomicAdd(&shadow[sid + o], s);
    atomicAdd(&shadow[sid + 64 + o], ss);
    uint4 pk;
    pk.x = pack2(v0, v1); pk.y = pack2(v2, v3); pk.z = pack2(v4, v5); pk.w = pack2(v6, v7);
    ((uint4*)(zout + (size_t)n * ROW))[o] = pk;
}

// ---------------- BN finalize: reduce 64 shadow copies -> per-channel a,b
__global__ __launch_bounds__(64) void k_bnfin(const float* __restrict__ shadow, const float* __restrict__ gamma,
                                              const float* __restrict__ beta, float* __restrict__ ab) {
    int c = threadIdx.x;
    float s = 0.f, ss = 0.f;
    for (int j = 0; j < 64; ++j) { s += shadow[j * 128 + c]; ss += shadow[j * 128 + 64 + c]; }
    float mean = s * (1.f / NM);
    float var = ss * (1.f / NM) - mean * mean;
    float a = gamma[c] * rsqrtf(var + 1e-5f);
    ab[c] = a;
    ab[64 + c] = beta[c] - mean * a;
}

// ---------------- pooling over nodes (bf16 raw z; BN applied in k_out)
__global__ __launch_bounds__(256) void k_pool(const uint* __restrict__ z2, float* __restrict__ pool) {
    int t = blockIdx.x * 256 + threadIdx.x;            // 65536 threads
    float s0 = 0.f, s1 = 0.f;
    for (int u = t; u < N_NODES * ROW / 2; u += 65536) {
        uint v = z2[u];
        s0 += bflo(v); s1 += bfhi(v);
    }
    int k2 = t & 255;                                   // element-pair index within a row
    atomicAdd(&pool[k2 * 2], s0);
    atomicAdd(&pool[k2 * 2 + 1], s1);
}

__global__ __launch_bounds__(64) void k_out(const float* __restrict__ pool, const float* __restrict__ ab4,
                                            const float* __restrict__ wout, const float* __restrict__ bout,
                                            float* __restrict__ out) {
    int c = threadIdx.x;
    float a = ab4[c], b = ab4[64 + c], wv = wout[c];
    for (int m = 0; m < 8; ++m) {
        float v = wv * (a * pool[c * 8 + m] * (1.f / N_NODES) + b);
        for (int off = 32; off > 0; off >>= 1) v += __shfl_down(v, off);
        if (c == 0) out[m] = 1.f / (1.f + expf(-(v + bout[0])));
    }
}

extern "C" void kernel_launch(void* const* d_in, const int* in_sizes, int n_in,
                              void* d_out, int out_size, void* d_ws, size_t ws_size,
                              hipStream_t stream) {
    const float* x     = (const float*)d_in[0];
    const int*   ei    = (const int*)d_in[1];
    const int*   srcp  = ei;
    const int*   dstp  = ei + N_EDGES;
    const float* w1_0  = (const float*)d_in[3];
    const float* w1    = (const float*)d_in[4];   // [4][64][64]
    const float* b1    = (const float*)d_in[5];   // [5][64]
    const float* w2    = (const float*)d_in[6];   // [5][64][64]
    const float* b2    = (const float*)d_in[7];
    const float* gamma = (const float*)d_in[8];
    const float* beta  = (const float*)d_in[9];
    const float* wout  = (const float*)d_in[10];
    const float* bout  = (const float*)d_in[11];
    float* out = (float*)d_out;

    char* ws = (char*)d_ws;
    size_t off = 0;
    auto alloc = [&](size_t bytes) -> void* {
        void* p = ws + off;
        off = (off + bytes + 255) & ~(size_t)255;
        return p;
    };
    ushort* zA  = (ushort*)alloc((size_t)N_NODES * ROW * 2);   // 20.5 MB bf16
    ushort* zB  = (ushort*)alloc((size_t)N_NODES * ROW * 2);   // 20.5 MB bf16
    float* zin0 = (float*)alloc((size_t)N_NODES * 8 * 4);
    int* deg      = (int*)alloc(N_NODES * 4);
    int* offs     = (int*)alloc(N_NODES * 4);
    int* cursor   = (int*)alloc(N_NODES * 4);
    int* esrc     = (int*)alloc(N_EDGES * 4);
    int* csum     = (int*)alloc(NCHUNK * 4);
    int* chunkoff = (int*)alloc(NCHUNK * 4);
    float* shadow = (float*)alloc(64 * 128 * 4);
    float* ab     = (float*)alloc(5 * 128 * 4);
    float* pool   = (float*)alloc(512 * 4);

    // CSR build
    hipMemsetAsync(deg, 0, N_NODES * 4, stream);
    hipMemsetAsync(cursor, 0, N_NODES * 4, stream);
    k_hist<<<(N_EDGES + 255) / 256, 256, 0, stream>>>(dstp, deg);
    k_csum<<<NCHUNK, 256, 0, stream>>>(deg, csum);
    k_cscan<<<1, 128, 0, stream>>>(csum, chunkoff);
    k_chunkscan<<<NCHUNK, 256, 0, stream>>>(deg, chunkoff, offs);
    k_fill<<<(N_EDGES + 255) / 256, 256, 0, stream>>>(srcp, dstp, offs, cursor, esrc);

    // layer 0
    k_agg0<<<N_NODES, 64, 0, stream>>>(x, offs, deg, esrc, zin0);
    hipMemsetAsync(shadow, 0, 64 * 128 * 4, stream);
    k_mlp0<<<N_NODES / 4, 256, 0, stream>>>(zin0, w1_0, b1, w2, b2, zA, shadow);
    k_bnfin<<<1, 64, 0, stream>>>(shadow, gamma, beta, ab);

    // layers 1..4 fused: gather+BN-fold+MLP; ping-pong zA<->zB
    const ushort* zin = zA;
    ushort* zo = zB;
    for (int i = 1; i <= 4; ++i) {
        hipMemsetAsync(shadow, 0, 64 * 128 * 4, stream);
        k_layer<<<N_NODES / 4, 256, 0, stream>>>(zin, ab + (i - 1) * 128, offs, deg, esrc,
                                                 w1 + (size_t)(i - 1) * 4096, b1 + i * 64,
                                                 w2 + (size_t)i * 4096, b2 + i * 64,
                                                 (ushort*)zo, shadow);
        k_bnfin<<<1, 64, 0, stream>>>(shadow, gamma + i * 64, beta + i * 64, ab + i * 128);
        const ushort* tmp = zin; zin = zo; zo = (ushort*)tmp;
    }
    // after 4 swaps, final raw z (layer 4) is back in zA

    // head
    hipMemsetAsync(pool, 0, 512 * 4, stream);
    k_pool<<<256, 256, 0, stream>>>((const uint*)zA, pool);
    k_out<<<1, 64, 0, stream>>>(pool, ab + 4 * 128, wout, bout, out);
}